// Round 11
// baseline (978.230 us; speedup 1.0000x reference)
//
#include <hip/hip_runtime.h>
#include <hip/hip_bf16.h>

#define N_NODES 50000
#define N_EDGES 400000
#define N_REL   3
#define NEG_SLOPE 0.2f
#define RP_STRIDE 50016           // row_ptr per-relation stride, 16B-aligned for int4
#define SCAN_BLOCKS 49            // ceil(50000/1024)
#define M_TILES 391               // ceil(50000/128)
#define MG_PER_XCD 49             // ceil(391/8)
#define M_PAD 50048               // 391*128: A-plane buffers padded so tail DMA is in-bounds

typedef __bf16 bf16x8 __attribute__((ext_vector_type(8)));
typedef float  f32x4  __attribute__((ext_vector_type(4)));

static __device__ __forceinline__ float bf2f(unsigned short u) {
  return __uint_as_float(((unsigned)u) << 16);
}
static __device__ __forceinline__ unsigned short f2bf(float f) {
  union { float f; unsigned u; } x; x.f = f;
  unsigned r = x.u + 0x7FFFu + ((x.u >> 16) & 1u);   // RNE (finite inputs)
  return (unsigned short)(r >> 16);
}
// async global->LDS DMA, 16B/lane, LDS dest = wave-uniform base + lane*16
static __device__ __forceinline__ void gld16(const void* g, unsigned short* lds) {
  __builtin_amdgcn_global_load_lds(
      (const __attribute__((address_space(1))) unsigned int*)g,
      (__attribute__((address_space(3))) unsigned int*)lds, 16, 0, 0);
}

// ---------------- CSR build ----------------

__global__ void count_kernel(const int* __restrict__ dst, int* __restrict__ cnt, int total) {
  int i = blockIdx.x * 256 + threadIdx.x;
  if (i < total) {
    int r = i / N_EDGES;
    atomicAdd(&cnt[r * N_NODES + dst[i]], 1);
  }
}

__global__ void block_reduce_kernel(const int* __restrict__ cnt, int* __restrict__ psum) {
  __shared__ int s[256];
  int r = blockIdx.x / SCAN_BLOCKS, b = blockIdx.x % SCAN_BLOCKS;
  int node = b * 1024 + threadIdx.x * 4;
  int sum = 0;
  if (node + 3 < N_NODES) {
    int4 v = *(const int4*)&cnt[r * N_NODES + node];
    sum = v.x + v.y + v.z + v.w;
  } else {
    for (int j = 0; j < 4; j++)
      if (node + j < N_NODES) sum += cnt[r * N_NODES + node + j];
  }
  s[threadIdx.x] = sum;
  __syncthreads();
  for (int o = 128; o > 0; o >>= 1) {
    if (threadIdx.x < o) s[threadIdx.x] += s[threadIdx.x + o];
    __syncthreads();
  }
  if (threadIdx.x == 0) psum[r * SCAN_BLOCKS + b] = s[0];
}

__global__ void psum_scan_kernel(int* __restrict__ psum, int* __restrict__ row_ptr) {
  int r = blockIdx.x, t = threadIdx.x;
  int v = (t < SCAN_BLOCKS) ? psum[r * SCAN_BLOCKS + t] : 0;
  int incl = v;
#pragma unroll
  for (int o = 1; o < 64; o <<= 1) {
    int u = __shfl_up(incl, o);
    if (t >= o) incl += u;
  }
  if (t < SCAN_BLOCKS) psum[r * SCAN_BLOCKS + t] = incl - v;
  if (t == SCAN_BLOCKS - 1) row_ptr[r * RP_STRIDE + N_NODES] = incl;
}

__global__ void scan_write_kernel(const int* __restrict__ cnt, const int* __restrict__ psum,
                                  int* __restrict__ row_ptr, int* __restrict__ cursor) {
  __shared__ int s[256];
  int r = blockIdx.x / SCAN_BLOCKS, b = blockIdx.x % SCAN_BLOCKS;
  int tid = threadIdx.x;
  int node = b * 1024 + tid * 4;
  int c[4] = {0, 0, 0, 0};
  if (node + 3 < N_NODES) {
    int4 v = *(const int4*)&cnt[r * N_NODES + node];
    c[0] = v.x; c[1] = v.y; c[2] = v.z; c[3] = v.w;
  } else {
    for (int j = 0; j < 4; j++)
      if (node + j < N_NODES) c[j] = cnt[r * N_NODES + node + j];
  }
  int tsum = c[0] + c[1] + c[2] + c[3];
  s[tid] = tsum;
  __syncthreads();
  for (int o = 1; o < 256; o <<= 1) {
    int v = (tid >= o) ? s[tid - o] : 0;
    __syncthreads();
    s[tid] += v;
    __syncthreads();
  }
  int run = s[tid] - tsum + psum[r * SCAN_BLOCKS + b];
  if (node + 3 < N_NODES) {
    int4 rp = make_int4(run, run + c[0], run + c[0] + c[1], run + c[0] + c[1] + c[2]);
    *(int4*)&row_ptr[r * RP_STRIDE + node] = rp;
    *(int4*)&cursor[r * N_NODES + node] = rp;
  } else {
    for (int j = 0; j < 4; j++) {
      if (node + j < N_NODES) {
        row_ptr[r * RP_STRIDE + node + j] = run;
        cursor[r * N_NODES + node + j] = run;
      }
      run += c[j];
    }
  }
}

__global__ void scatter_kernel(const int* __restrict__ src, const int* __restrict__ dst,
                               int* __restrict__ cursor, int* __restrict__ col, int total) {
  int i = blockIdx.x * 256 + threadIdx.x;
  if (i < total) {
    int r = i / N_EDGES;
    int d = dst[i];
    int pos = atomicAdd(&cursor[r * N_NODES + d], 1);
    col[r * N_EDGES + pos] = src[i];
  }
}

// ---------------- x -> bf16 hi/lo planes (once) ----------------

__global__ void xsplit_kernel(const float* __restrict__ x,
                              unsigned short* __restrict__ xh, unsigned short* __restrict__ xl) {
  int i = blockIdx.x * 256 + threadIdx.x;   // float4 index over M_PAD*64
  int row = i >> 6;
  float4 v = make_float4(0.f, 0.f, 0.f, 0.f);
  if (row < N_NODES) v = ((const float4*)x)[i];
  ushort4 h, l;
  h.x = f2bf(v.x); l.x = f2bf(v.x - bf2f(h.x));
  h.y = f2bf(v.y); l.y = f2bf(v.y - bf2f(h.y));
  h.z = f2bf(v.z); l.z = f2bf(v.z - bf2f(h.z));
  h.w = f2bf(v.w); l.w = f2bf(v.w - bf2f(h.w));
  ((ushort4*)xh)[i] = h;
  ((ushort4*)xl)[i] = l;
}

// ---------------- weight transpose + hi/lo bf16 split ----------------

__global__ void wsplit_kernel(const float* __restrict__ W0, const float* __restrict__ W1,
                              const float* __restrict__ W2,
                              unsigned short* __restrict__ Whi, unsigned short* __restrict__ Wlo) {
  __shared__ float tile[32][33];
  int mat = blockIdx.x >> 6;           // 0..8
  int t = blockIdx.x & 63;
  int k0 = (t >> 3) * 32, n0 = (t & 7) * 32;
  const float* W = (mat < 3 ? W0 : (mat < 6 ? W1 : W2)) + (size_t)(mat % 3) * 65536;
  int row = threadIdx.x >> 3;          // 0..31 (k)
  int c4 = threadIdx.x & 7;            // 0..7
  float4 v = *(const float4*)&W[(k0 + row) * 256 + n0 + c4 * 4];
  tile[c4 * 4 + 0][row] = v.x;
  tile[c4 * 4 + 1][row] = v.y;
  tile[c4 * 4 + 2][row] = v.z;
  tile[c4 * 4 + 3][row] = v.w;
  __syncthreads();
  int nl = threadIdx.x >> 3;           // 0..31 (n)
  int kq = threadIdx.x & 7;
  ushort4 h, l;
  float a0 = tile[nl][kq * 4 + 0], a1 = tile[nl][kq * 4 + 1];
  float a2 = tile[nl][kq * 4 + 2], a3 = tile[nl][kq * 4 + 3];
  h.x = f2bf(a0); l.x = f2bf(a0 - bf2f(h.x));
  h.y = f2bf(a1); l.y = f2bf(a1 - bf2f(h.y));
  h.z = f2bf(a2); l.z = f2bf(a2 - bf2f(h.z));
  h.w = f2bf(a3); l.w = f2bf(a3 - bf2f(h.w));
  size_t o = (size_t)mat * 65536 + (n0 + nl) * 256 + k0 + kq * 4;
  *(ushort4*)&Whi[o] = h;
  *(ushort4*)&Wlo[o] = l;
}

// ---------------- merged GEMM (N,256)@(256,768) + fused el/er + bf16 feat ----------------
// Staging = global_load_lds 16B DMA. LDS tiles MUST stay unpadded (LDS_S=32).

#define LDS_S 32
#define LDT  136  // transpose row stride (ushorts); 272B keeps 16B alignment

__global__ __launch_bounds__(256, 3) void gemm_mfma_kernel(
    const unsigned short* __restrict__ Ah, const unsigned short* __restrict__ Al,
    const unsigned short* __restrict__ Bhi, const unsigned short* __restrict__ Blo,
    const float* __restrict__ alf, const float* __restrict__ arf,
    unsigned short* __restrict__ Cb, float* __restrict__ el, float* __restrict__ er, int M) {
  __shared__ __align__(16) unsigned short lds[128 * LDT];  // 34816 B (>= 4*128*32*2)
  unsigned short* As_h = lds;
  unsigned short* As_l = lds + 128 * LDS_S;
  unsigned short* Bs_h = lds + 2 * 128 * LDS_S;
  unsigned short* Bs_l = lds + 3 * 128 * LDS_S;

  const int wid = blockIdx.x;
  const int xcd = wid & 7, local = wid >> 3;
  const int m_t = (local / 6) * 8 + xcd;
  if (m_t >= M_TILES) return;
  const int n_t = local % 6;
  const int m0 = m_t * 128, n0 = n_t * 128;

  const int tid = threadIdx.x;
  const int wave = tid >> 6, lane = tid & 63;
  const int quad = lane >> 4, l16 = lane & 15;
  const int wr = wave & 1, wc = wave >> 1;

  f32x4 acc[4][4];
#pragma unroll
  for (int i = 0; i < 4; i++)
#pragma unroll
    for (int j = 0; j < 4; j++) acc[i][j] = (f32x4){0.f, 0.f, 0.f, 0.f};

  for (int kb = 0; kb < 8; kb++) {
    int k0 = kb * 32;
#pragma unroll
    for (int i = 0; i < 2; i++) {
      int ch = wave * 2 + i;
      int c = ch * 64 + lane;
      int row = c >> 2, k16 = c & 3;
      size_t gA = ((size_t)(m0 + row) * 256 + k0) * 2 + (size_t)k16 * 16;  // bytes
      size_t gB = ((size_t)(n0 + row) * 256 + k0) * 2 + (size_t)k16 * 16;
      gld16((const char*)Ah + gA, &As_h[ch * 512]);
      gld16((const char*)Al + gA, &As_l[ch * 512]);
      gld16((const char*)Bhi + gB, &Bs_h[ch * 512]);
      gld16((const char*)Blo + gB, &Bs_l[ch * 512]);
    }
    __syncthreads();

    bf16x8 ah[4], al_[4], bh[4], bl[4];
#pragma unroll
    for (int t = 0; t < 4; t++) {
      int arow = (wr * 64 + t * 16 + l16) * LDS_S + quad * 8;
      int brow = (wc * 64 + t * 16 + l16) * LDS_S + quad * 8;
      ah[t] = *(const bf16x8*)&As_h[arow];
      al_[t] = *(const bf16x8*)&As_l[arow];
      bh[t] = *(const bf16x8*)&Bs_h[brow];
      bl[t] = *(const bf16x8*)&Bs_l[brow];
    }
#pragma unroll
    for (int mi = 0; mi < 4; mi++)
#pragma unroll
      for (int ni = 0; ni < 4; ni++) {
        acc[mi][ni] = __builtin_amdgcn_mfma_f32_16x16x32_bf16(ah[mi], bl[ni], acc[mi][ni], 0, 0, 0);
        acc[mi][ni] = __builtin_amdgcn_mfma_f32_16x16x32_bf16(al_[mi], bh[ni], acc[mi][ni], 0, 0, 0);
        acc[mi][ni] = __builtin_amdgcn_mfma_f32_16x16x32_bf16(ah[mi], bh[ni], acc[mi][ni], 0, 0, 0);
      }
    __syncthreads();
  }

  // ---- fused el/er: head-chunk hw = 2*n_t + wc; rel = hw>>2, head = hw&3 ----
  const int hw = n_t * 2 + wc;
  const int rel = hw >> 2, hh = hw & 3;
  float alw[4], arw[4];
#pragma unroll
  for (int ni = 0; ni < 4; ni++) {
    int gc = n0 + wc * 64 + ni * 16 + l16;
    alw[ni] = alf[gc]; arw[ni] = arf[gc];
  }
  float pel[4][4], per_[4][4];
#pragma unroll
  for (int mi = 0; mi < 4; mi++)
#pragma unroll
    for (int r = 0; r < 4; r++) {
      float se = 0.f, sr = 0.f;
#pragma unroll
      for (int ni = 0; ni < 4; ni++) {
        se += acc[mi][ni][r] * alw[ni];
        sr += acc[mi][ni][r] * arw[ni];
      }
      pel[mi][r] = se; per_[mi][r] = sr;
    }
#pragma unroll
  for (int off = 1; off < 16; off <<= 1)
#pragma unroll
    for (int mi = 0; mi < 4; mi++)
#pragma unroll
      for (int r = 0; r < 4; r++) {
        pel[mi][r] += __shfl_xor(pel[mi][r], off);
        per_[mi][r] += __shfl_xor(per_[mi][r], off);
      }
  if (l16 == 0) {
#pragma unroll
    for (int mi = 0; mi < 4; mi++)
#pragma unroll
      for (int r = 0; r < 4; r++) {
        int gm = m0 + wr * 64 + mi * 16 + quad * 4 + r;
        if (gm < M) {
          size_t o = ((size_t)rel * N_NODES + gm) * 4 + hh;  // [rel][n][4]
          el[o] = pel[mi][r];
          er[o] = per_[mi][r];
        }
      }
  }

  // ---- feat -> bf16 via LDS transpose, coalesced store (row stride 768) ----
#pragma unroll
  for (int mi = 0; mi < 4; mi++) {
    int row = wr * 64 + mi * 16 + quad * 4;
#pragma unroll
    for (int ni = 0; ni < 4; ni++) {
      int c = wc * 64 + ni * 16 + l16;
#pragma unroll
      for (int r = 0; r < 4; r++)
        lds[(row + r) * LDT + c] = f2bf(acc[mi][ni][r]);
    }
  }
  __syncthreads();
#pragma unroll
  for (int it = 0; it < 8; it++) {
    int chunk = tid + 256 * it;           // 0..2047
    int row = chunk >> 4, c8 = (chunk & 15) * 8;
    int gm = m0 + row;
    if (gm < M)
      *(uint4*)&Cb[(size_t)gm * 768 + n0 + c8] = *(const uint4*)&lds[row * LDT + c8];
  }
}

// ---------------- fused aggregation, LDS-free ----------------
// Phase 1 (lanes=edges): denominators only (normalization is linear -> applied
//   after the sum). Phase 2: 2 edges in parallel per instruction — lane =
//   (edge-of-pair esel = L>>5) x (feature chunk c = L&31, 8 feats), 16B gathers,
//   4 edges/iteration for MLP; p recomputed per edge (el is L2-resident).

__global__ void agg_kernel(const unsigned short* __restrict__ featb,
                           const float* __restrict__ el, const float* __restrict__ er,
                           const int* __restrict__ row_ptr, const int* __restrict__ col,
                           const float* __restrict__ bias,
                           unsigned short* __restrict__ hH, unsigned short* __restrict__ hL,
                           float* __restrict__ outF, int final_layer) {
  int w = threadIdx.x >> 6;
  int n = blockIdx.x * 4 + w;
  int L = threadIdx.x & 63;
  if (n >= N_NODES) return;
  const int c = L & 31;        // feature chunk: feats c*8..c*8+7
  const int esel = L >> 5;     // which edge of the pair
  const int hsel = c >> 3;     // head of this chunk

  int s0r[N_REL], s1r[N_REL];
  float invr[N_REL];
  float ernh_r[N_REL];
  // ---- phase 1: denominators ----
#pragma unroll
  for (int r = 0; r < N_REL; r++) {
    int s0 = row_ptr[r * RP_STRIDE + n], s1 = row_ptr[r * RP_STRIDE + n + 1];
    s0r[r] = s0; s1r[r] = s1;
    float4 ern = ((const float4*)er)[(size_t)r * N_NODES + n];
    ernh_r[r] = (hsel == 0) ? ern.x : (hsel == 1) ? ern.y : (hsel == 2) ? ern.z : ern.w;
    const int* cp = col + (size_t)r * N_EDGES;
    float d0 = 0.f, d1 = 0.f, d2 = 0.f, d3 = 0.f;
    for (int base = s0; base < s1; base += 64) {
      int i = base + L;
      if (i < s1) {
        int s = cp[i];
        float4 els = ((const float4*)el)[(size_t)r * N_NODES + s];
        float e0 = els.x + ern.x; e0 = e0 > 0.f ? e0 : NEG_SLOPE * e0;
        float e1 = els.y + ern.y; e1 = e1 > 0.f ? e1 : NEG_SLOPE * e1;
        float e2 = els.z + ern.z; e2 = e2 > 0.f ? e2 : NEG_SLOPE * e2;
        float e3 = els.w + ern.w; e3 = e3 > 0.f ? e3 : NEG_SLOPE * e3;
        d0 += __expf(e0); d1 += __expf(e1); d2 += __expf(e2); d3 += __expf(e3);
      }
    }
#pragma unroll
    for (int o = 1; o < 64; o <<= 1) {
      d0 += __shfl_xor(d0, o); d1 += __shfl_xor(d1, o);
      d2 += __shfl_xor(d2, o); d3 += __shfl_xor(d3, o);
    }
    float dsel = (hsel == 0) ? d0 : (hsel == 1) ? d1 : (hsel == 2) ? d2 : d3;
    invr[r] = 1.0f / fmaxf(dsel, 1e-30f);
  }

  // ---- phase 2: weighted gather-sum, 2 edges x 16B per instruction ----
  const float third = 1.0f / 3.0f;
  float os[8];
#pragma unroll
  for (int j = 0; j < 8; j++) os[j] = 0.f;
#pragma unroll
  for (int r = 0; r < N_REL; r++) {
    int s0 = s0r[r], s1 = s1r[r];
    const int* cp = col + (size_t)r * N_EDGES;
    const unsigned short* fbase = featb + r * 256 + c * 8;
    const float* elh_base = el + (size_t)r * N_NODES * 4 + hsel;
    float ernh = ernh_r[r];
    float acc[8];
#pragma unroll
    for (int j = 0; j < 8; j++) acc[j] = 0.f;
    int i = s0;
    for (; i + 3 < s1; i += 4) {       // 4 edges/iter: 2 per lane-group, 2 iter-independent
      int iA = i + esel, iB = i + 2 + esel;
      int sA = cp[iA], sB = cp[iB];
      float eA = elh_base[(size_t)sA * 4] + ernh; eA = eA > 0.f ? eA : NEG_SLOPE * eA;
      float eB = elh_base[(size_t)sB * 4] + ernh; eB = eB > 0.f ? eB : NEG_SLOPE * eB;
      float pA = __expf(eA), pB = __expf(eB);
      uint4 fA = *(const uint4*)&fbase[(size_t)sA * 768];
      uint4 fB = *(const uint4*)&fbase[(size_t)sB * 768];
      acc[0] += pA * bf2f((unsigned short)fA.x) + pB * bf2f((unsigned short)fB.x);
      acc[1] += pA * bf2f((unsigned short)(fA.x >> 16)) + pB * bf2f((unsigned short)(fB.x >> 16));
      acc[2] += pA * bf2f((unsigned short)fA.y) + pB * bf2f((unsigned short)fB.y);
      acc[3] += pA * bf2f((unsigned short)(fA.y >> 16)) + pB * bf2f((unsigned short)(fB.y >> 16));
      acc[4] += pA * bf2f((unsigned short)fA.z) + pB * bf2f((unsigned short)fB.z);
      acc[5] += pA * bf2f((unsigned short)(fA.z >> 16)) + pB * bf2f((unsigned short)(fB.z >> 16));
      acc[6] += pA * bf2f((unsigned short)fA.w) + pB * bf2f((unsigned short)fB.w);
      acc[7] += pA * bf2f((unsigned short)(fA.w >> 16)) + pB * bf2f((unsigned short)(fB.w >> 16));
    }
    for (; i < s1; i += 2) {
      int ii = i + esel;
      if (ii < s1) {
        int s = cp[ii];
        float e = elh_base[(size_t)s * 4] + ernh; e = e > 0.f ? e : NEG_SLOPE * e;
        float pw = __expf(e);
        uint4 fv = *(const uint4*)&fbase[(size_t)s * 768];
        acc[0] += pw * bf2f((unsigned short)fv.x);
        acc[1] += pw * bf2f((unsigned short)(fv.x >> 16));
        acc[2] += pw * bf2f((unsigned short)fv.y);
        acc[3] += pw * bf2f((unsigned short)(fv.y >> 16));
        acc[4] += pw * bf2f((unsigned short)fv.z);
        acc[5] += pw * bf2f((unsigned short)(fv.z >> 16));
        acc[6] += pw * bf2f((unsigned short)fv.w);
        acc[7] += pw * bf2f((unsigned short)(fv.w >> 16));
      }
    }
    // combine the two edge subsets
#pragma unroll
    for (int j = 0; j < 8; j++) acc[j] += __shfl_xor(acc[j], 32);
    float inv = invr[r];
    const float* bb = bias + r * 256 + c * 8;
    float4 b0 = *(const float4*)bb, b1 = *(const float4*)(bb + 4);
    float bv[8] = {b0.x, b0.y, b0.z, b0.w, b1.x, b1.y, b1.z, b1.w};
#pragma unroll
    for (int j = 0; j < 8; j++) {
      float o = acc[j] * inv + bv[j];
      o = o > 0.f ? o : __expf(o) - 1.0f;  // elu
      os[j] += o * third;
    }
  }

  if (final_layer) {
    // head mean: chunks with equal c&7 across heads differ in lane bits 3,4
#pragma unroll
    for (int j = 0; j < 8; j++) {
      os[j] += __shfl_xor(os[j], 8);
      os[j] += __shfl_xor(os[j], 16);
    }
    if (L < 8) {
      float4 v0 = make_float4(0.25f * os[0], 0.25f * os[1], 0.25f * os[2], 0.25f * os[3]);
      float4 v1 = make_float4(0.25f * os[4], 0.25f * os[5], 0.25f * os[6], 0.25f * os[7]);
      *(float4*)&outF[(size_t)n * 64 + L * 8] = v0;
      *(float4*)&outF[(size_t)n * 64 + L * 8 + 4] = v1;
    }
  } else {
    if (L < 32) {
      ushort4 h0, h1, l0, l1;
      h0.x = f2bf(os[0]); l0.x = f2bf(os[0] - bf2f(h0.x));
      h0.y = f2bf(os[1]); l0.y = f2bf(os[1] - bf2f(h0.y));
      h0.z = f2bf(os[2]); l0.z = f2bf(os[2] - bf2f(h0.z));
      h0.w = f2bf(os[3]); l0.w = f2bf(os[3] - bf2f(h0.w));
      h1.x = f2bf(os[4]); l1.x = f2bf(os[4] - bf2f(h1.x));
      h1.y = f2bf(os[5]); l1.y = f2bf(os[5] - bf2f(h1.y));
      h1.z = f2bf(os[6]); l1.z = f2bf(os[6] - bf2f(h1.z));
      h1.w = f2bf(os[7]); l1.w = f2bf(os[7] - bf2f(h1.w));
      *(ushort4*)&hH[(size_t)n * 256 + c * 8] = h0;
      *(ushort4*)&hH[(size_t)n * 256 + c * 8 + 4] = h1;
      *(ushort4*)&hL[(size_t)n * 256 + c * 8] = l0;
      *(ushort4*)&hL[(size_t)n * 256 + c * 8 + 4] = l1;
    }
  }
}

// ---------------- launch ----------------

extern "C" void kernel_launch(void* const* d_in, const int* in_sizes, int n_in,
                              void* d_out, int out_size, void* d_ws, size_t ws_size,
                              hipStream_t stream) {
  (void)in_sizes; (void)n_in; (void)out_size; (void)ws_size;
  const float* x = (const float*)d_in[0];
  const int* src = (const int*)d_in[1];
  const int* dst = (const int*)d_in[2];
  const float* Wl[3]  = {(const float*)d_in[3], (const float*)d_in[7], (const float*)d_in[11]};
  const float* alL[3] = {(const float*)d_in[4], (const float*)d_in[8], (const float*)d_in[12]};
  const float* arL[3] = {(const float*)d_in[5], (const float*)d_in[9], (const float*)d_in[13]};
  const float* bL[3]  = {(const float*)d_in[6], (const float*)d_in[10], (const float*)d_in[14]};

  char* p = (char*)d_ws;
  auto alloc = [&](size_t bytes) {
    char* q = p;
    p += (bytes + 255) & ~size_t(255);
    return q;
  };
  unsigned short* xh = (unsigned short*)alloc((size_t)M_PAD * 256 * 2);
  unsigned short* xl = (unsigned short*)alloc((size_t)M_PAD * 256 * 2);
  unsigned short* hH = (unsigned short*)alloc((size_t)M_PAD * 256 * 2);
  unsigned short* hL = (unsigned short*)alloc((size_t)M_PAD * 256 * 2);
  unsigned short* featb = (unsigned short*)alloc((size_t)N_NODES * 768 * 2);
  float* el      = (float*)alloc((size_t)N_REL * N_NODES * 4 * 4);
  float* er      = (float*)alloc((size_t)N_REL * N_NODES * 4 * 4);
  int*   cnt     = (int*)alloc((size_t)N_REL * N_NODES * 4);
  int*   cursor  = (int*)alloc((size_t)N_REL * N_NODES * 4);
  int*   row_ptr = (int*)alloc((size_t)N_REL * RP_STRIDE * 4 + 64);
  int*   col     = (int*)alloc((size_t)N_REL * N_EDGES * 4);
  int*   psum    = (int*)alloc((size_t)N_REL * SCAN_BLOCKS * 4);
  unsigned short* Whi = (unsigned short*)alloc((size_t)9 * 65536 * 2);
  unsigned short* Wlo = (unsigned short*)alloc((size_t)9 * 65536 * 2);

  hipMemsetAsync(cnt, 0, (size_t)N_REL * N_NODES * 4, stream);
  const int totalE = N_REL * N_EDGES;
  count_kernel<<<(totalE + 255) / 256, 256, 0, stream>>>(dst, cnt, totalE);
  block_reduce_kernel<<<N_REL * SCAN_BLOCKS, 256, 0, stream>>>(cnt, psum);
  psum_scan_kernel<<<N_REL, 64, 0, stream>>>(psum, row_ptr);
  scan_write_kernel<<<N_REL * SCAN_BLOCKS, 256, 0, stream>>>(cnt, psum, row_ptr, cursor);
  scatter_kernel<<<(totalE + 255) / 256, 256, 0, stream>>>(src, dst, cursor, col, totalE);
  wsplit_kernel<<<9 * 64, 256, 0, stream>>>(Wl[0], Wl[1], Wl[2], Whi, Wlo);
  xsplit_kernel<<<M_PAD * 64 / 256, 256, 0, stream>>>(x, xh, xl);

  const int nodeBlocks = (N_NODES + 3) / 4;
  const int gemmBlocks = MG_PER_XCD * 6 * 8;   // 2352
  for (int l = 0; l < 3; l++) {
    const unsigned short* Ahp = (l == 0) ? xh : hH;
    const unsigned short* Alp = (l == 0) ? xl : hL;
    gemm_mfma_kernel<<<gemmBlocks, 256, 0, stream>>>(
        Ahp, Alp, Whi + (size_t)l * 3 * 65536, Wlo + (size_t)l * 3 * 65536,
        alL[l], arL[l], featb, el, er, N_NODES);
    agg_kernel<<<nodeBlocks, 256, 0, stream>>>(
        featb, el, er, row_ptr, col, bL[l], hH, hL, (float*)d_out, l == 2);
  }
}

// Round 12
// 856.220 us; speedup vs baseline: 1.1425x; 1.1425x over previous
//
#include <hip/hip_runtime.h>
#include <hip/hip_bf16.h>

#define N_NODES 50000
#define N_EDGES 400000
#define N_REL   3
#define NEG_SLOPE 0.2f
#define RP_STRIDE 50016           // row_ptr per-relation stride, 16B-aligned for int4
#define SCAN_BLOCKS 49            // ceil(50000/1024)
#define M_TILES 391               // ceil(50000/128)
#define MG_PER_XCD 49             // ceil(391/8)
#define M_PAD 50048               // 391*128: A-plane buffers padded so tail DMA is in-bounds
#define MAXDEG 48                 // LDS alpha capacity; deg~Poisson(8), P(>48)~0; fallback kept

typedef __bf16 bf16x8 __attribute__((ext_vector_type(8)));
typedef float  f32x4  __attribute__((ext_vector_type(4)));

static __device__ __forceinline__ float bf2f(unsigned short u) {
  return __uint_as_float(((unsigned)u) << 16);
}
static __device__ __forceinline__ unsigned short f2bf(float f) {
  union { float f; unsigned u; } x; x.f = f;
  unsigned r = x.u + 0x7FFFu + ((x.u >> 16) & 1u);   // RNE (finite inputs)
  return (unsigned short)(r >> 16);
}
// async global->LDS DMA, 16B/lane, LDS dest = wave-uniform base + lane*16
static __device__ __forceinline__ void gld16(const void* g, unsigned short* lds) {
  __builtin_amdgcn_global_load_lds(
      (const __attribute__((address_space(1))) unsigned int*)g,
      (__attribute__((address_space(3))) unsigned int*)lds, 16, 0, 0);
}

// ---------------- CSR build ----------------

__global__ void count_kernel(const int* __restrict__ dst, int* __restrict__ cnt, int total) {
  int i = blockIdx.x * 256 + threadIdx.x;
  if (i < total) {
    int r = i / N_EDGES;
    atomicAdd(&cnt[r * N_NODES + dst[i]], 1);
  }
}

__global__ void block_reduce_kernel(const int* __restrict__ cnt, int* __restrict__ psum) {
  __shared__ int s[256];
  int r = blockIdx.x / SCAN_BLOCKS, b = blockIdx.x % SCAN_BLOCKS;
  int node = b * 1024 + threadIdx.x * 4;
  int sum = 0;
  if (node + 3 < N_NODES) {
    int4 v = *(const int4*)&cnt[r * N_NODES + node];
    sum = v.x + v.y + v.z + v.w;
  } else {
    for (int j = 0; j < 4; j++)
      if (node + j < N_NODES) sum += cnt[r * N_NODES + node + j];
  }
  s[threadIdx.x] = sum;
  __syncthreads();
  for (int o = 128; o > 0; o >>= 1) {
    if (threadIdx.x < o) s[threadIdx.x] += s[threadIdx.x + o];
    __syncthreads();
  }
  if (threadIdx.x == 0) psum[r * SCAN_BLOCKS + b] = s[0];
}

__global__ void psum_scan_kernel(int* __restrict__ psum, int* __restrict__ row_ptr) {
  int r = blockIdx.x, t = threadIdx.x;
  int v = (t < SCAN_BLOCKS) ? psum[r * SCAN_BLOCKS + t] : 0;
  int incl = v;
#pragma unroll
  for (int o = 1; o < 64; o <<= 1) {
    int u = __shfl_up(incl, o);
    if (t >= o) incl += u;
  }
  if (t < SCAN_BLOCKS) psum[r * SCAN_BLOCKS + t] = incl - v;
  if (t == SCAN_BLOCKS - 1) row_ptr[r * RP_STRIDE + N_NODES] = incl;
}

__global__ void scan_write_kernel(const int* __restrict__ cnt, const int* __restrict__ psum,
                                  int* __restrict__ row_ptr, int* __restrict__ cursor) {
  __shared__ int s[256];
  int r = blockIdx.x / SCAN_BLOCKS, b = blockIdx.x % SCAN_BLOCKS;
  int tid = threadIdx.x;
  int node = b * 1024 + tid * 4;
  int c[4] = {0, 0, 0, 0};
  if (node + 3 < N_NODES) {
    int4 v = *(const int4*)&cnt[r * N_NODES + node];
    c[0] = v.x; c[1] = v.y; c[2] = v.z; c[3] = v.w;
  } else {
    for (int j = 0; j < 4; j++)
      if (node + j < N_NODES) c[j] = cnt[r * N_NODES + node + j];
  }
  int tsum = c[0] + c[1] + c[2] + c[3];
  s[tid] = tsum;
  __syncthreads();
  for (int o = 1; o < 256; o <<= 1) {
    int v = (tid >= o) ? s[tid - o] : 0;
    __syncthreads();
    s[tid] += v;
    __syncthreads();
  }
  int run = s[tid] - tsum + psum[r * SCAN_BLOCKS + b];
  if (node + 3 < N_NODES) {
    int4 rp = make_int4(run, run + c[0], run + c[0] + c[1], run + c[0] + c[1] + c[2]);
    *(int4*)&row_ptr[r * RP_STRIDE + node] = rp;
    *(int4*)&cursor[r * N_NODES + node] = rp;
  } else {
    for (int j = 0; j < 4; j++) {
      if (node + j < N_NODES) {
        row_ptr[r * RP_STRIDE + node + j] = run;
        cursor[r * N_NODES + node + j] = run;
      }
      run += c[j];
    }
  }
}

__global__ void scatter_kernel(const int* __restrict__ src, const int* __restrict__ dst,
                               int* __restrict__ cursor, int* __restrict__ col, int total) {
  int i = blockIdx.x * 256 + threadIdx.x;
  if (i < total) {
    int r = i / N_EDGES;
    int d = dst[i];
    int pos = atomicAdd(&cursor[r * N_NODES + d], 1);
    col[r * N_EDGES + pos] = src[i];
  }
}

// ---------------- x -> bf16 hi plane (once; lo plane dropped, see GEMM note) --------

__global__ void xsplit_kernel(const float* __restrict__ x, unsigned short* __restrict__ xh) {
  int i = blockIdx.x * 256 + threadIdx.x;   // float4 index over M_PAD*64
  int row = i >> 6;
  float4 v = make_float4(0.f, 0.f, 0.f, 0.f);
  if (row < N_NODES) v = ((const float4*)x)[i];
  ushort4 h;
  h.x = f2bf(v.x); h.y = f2bf(v.y); h.z = f2bf(v.z); h.w = f2bf(v.w);
  ((ushort4*)xh)[i] = h;
}

// ---------------- weight transpose + hi/lo bf16 split ----------------

__global__ void wsplit_kernel(const float* __restrict__ W0, const float* __restrict__ W1,
                              const float* __restrict__ W2,
                              unsigned short* __restrict__ Whi, unsigned short* __restrict__ Wlo) {
  __shared__ float tile[32][33];
  int mat = blockIdx.x >> 6;           // 0..8
  int t = blockIdx.x & 63;
  int k0 = (t >> 3) * 32, n0 = (t & 7) * 32;
  const float* W = (mat < 3 ? W0 : (mat < 6 ? W1 : W2)) + (size_t)(mat % 3) * 65536;
  int row = threadIdx.x >> 3;          // 0..31 (k)
  int c4 = threadIdx.x & 7;            // 0..7
  float4 v = *(const float4*)&W[(k0 + row) * 256 + n0 + c4 * 4];
  tile[c4 * 4 + 0][row] = v.x;
  tile[c4 * 4 + 1][row] = v.y;
  tile[c4 * 4 + 2][row] = v.z;
  tile[c4 * 4 + 3][row] = v.w;
  __syncthreads();
  int nl = threadIdx.x >> 3;           // 0..31 (n)
  int kq = threadIdx.x & 7;
  ushort4 h, l;
  float a0 = tile[nl][kq * 4 + 0], a1 = tile[nl][kq * 4 + 1];
  float a2 = tile[nl][kq * 4 + 2], a3 = tile[nl][kq * 4 + 3];
  h.x = f2bf(a0); l.x = f2bf(a0 - bf2f(h.x));
  h.y = f2bf(a1); l.y = f2bf(a1 - bf2f(h.y));
  h.z = f2bf(a2); l.z = f2bf(a2 - bf2f(h.z));
  h.w = f2bf(a3); l.w = f2bf(a3 - bf2f(h.w));
  size_t o = (size_t)mat * 65536 + (n0 + nl) * 256 + k0 + kq * 4;
  *(ushort4*)&Whi[o] = h;
  *(ushort4*)&Wlo[o] = l;
}

// ---------------- merged GEMM (N,256)@(256,768) + fused el/er + bf16 feat ----------------
// 2-term split: D = ah*bh + ah*bl (A-lo dropped — feat is consumed as bf16
// downstream, so A-truncation error ~doubles existing quantization, stays
// under threshold). Staging = global_load_lds 16B DMA, 3 planes.

#define LDS_S 32
#define LDT  136  // transpose row stride (ushorts); 272B keeps 16B alignment

__global__ __launch_bounds__(256, 3) void gemm_mfma_kernel(
    const unsigned short* __restrict__ Ah,
    const unsigned short* __restrict__ Bhi, const unsigned short* __restrict__ Blo,
    const float* __restrict__ alf, const float* __restrict__ arf,
    unsigned short* __restrict__ Cb, float* __restrict__ el, float* __restrict__ er, int M) {
  __shared__ __align__(16) unsigned short lds[128 * LDT];  // 34816 B (>= 3*128*32*2)
  unsigned short* As_h = lds;
  unsigned short* Bs_h = lds + 128 * LDS_S;
  unsigned short* Bs_l = lds + 2 * 128 * LDS_S;

  const int wid = blockIdx.x;
  const int xcd = wid & 7, local = wid >> 3;
  const int m_t = (local / 6) * 8 + xcd;
  if (m_t >= M_TILES) return;
  const int n_t = local % 6;
  const int m0 = m_t * 128, n0 = n_t * 128;

  const int tid = threadIdx.x;
  const int wave = tid >> 6, lane = tid & 63;
  const int quad = lane >> 4, l16 = lane & 15;
  const int wr = wave & 1, wc = wave >> 1;

  f32x4 acc[4][4];
#pragma unroll
  for (int i = 0; i < 4; i++)
#pragma unroll
    for (int j = 0; j < 4; j++) acc[i][j] = (f32x4){0.f, 0.f, 0.f, 0.f};

  for (int kb = 0; kb < 8; kb++) {
    int k0 = kb * 32;
#pragma unroll
    for (int i = 0; i < 2; i++) {
      int ch = wave * 2 + i;
      int c = ch * 64 + lane;
      int row = c >> 2, k16 = c & 3;
      size_t gA = ((size_t)(m0 + row) * 256 + k0) * 2 + (size_t)k16 * 16;  // bytes
      size_t gB = ((size_t)(n0 + row) * 256 + k0) * 2 + (size_t)k16 * 16;
      gld16((const char*)Ah + gA, &As_h[ch * 512]);
      gld16((const char*)Bhi + gB, &Bs_h[ch * 512]);
      gld16((const char*)Blo + gB, &Bs_l[ch * 512]);
    }
    __syncthreads();

    bf16x8 ah[4], bh[4], bl[4];
#pragma unroll
    for (int t = 0; t < 4; t++) {
      int arow = (wr * 64 + t * 16 + l16) * LDS_S + quad * 8;
      int brow = (wc * 64 + t * 16 + l16) * LDS_S + quad * 8;
      ah[t] = *(const bf16x8*)&As_h[arow];
      bh[t] = *(const bf16x8*)&Bs_h[brow];
      bl[t] = *(const bf16x8*)&Bs_l[brow];
    }
#pragma unroll
    for (int mi = 0; mi < 4; mi++)
#pragma unroll
      for (int ni = 0; ni < 4; ni++) {
        acc[mi][ni] = __builtin_amdgcn_mfma_f32_16x16x32_bf16(ah[mi], bl[ni], acc[mi][ni], 0, 0, 0);
        acc[mi][ni] = __builtin_amdgcn_mfma_f32_16x16x32_bf16(ah[mi], bh[ni], acc[mi][ni], 0, 0, 0);
      }
    __syncthreads();
  }

  // ---- fused el/er: head-chunk hw = 2*n_t + wc; rel = hw>>2, head = hw&3 ----
  const int hw = n_t * 2 + wc;
  const int rel = hw >> 2, hh = hw & 3;
  float alw[4], arw[4];
#pragma unroll
  for (int ni = 0; ni < 4; ni++) {
    int gc = n0 + wc * 64 + ni * 16 + l16;
    alw[ni] = alf[gc]; arw[ni] = arf[gc];
  }
  float pel[4][4], per_[4][4];
#pragma unroll
  for (int mi = 0; mi < 4; mi++)
#pragma unroll
    for (int r = 0; r < 4; r++) {
      float se = 0.f, sr = 0.f;
#pragma unroll
      for (int ni = 0; ni < 4; ni++) {
        se += acc[mi][ni][r] * alw[ni];
        sr += acc[mi][ni][r] * arw[ni];
      }
      pel[mi][r] = se; per_[mi][r] = sr;
    }
#pragma unroll
  for (int off = 1; off < 16; off <<= 1)
#pragma unroll
    for (int mi = 0; mi < 4; mi++)
#pragma unroll
      for (int r = 0; r < 4; r++) {
        pel[mi][r] += __shfl_xor(pel[mi][r], off);
        per_[mi][r] += __shfl_xor(per_[mi][r], off);
      }
  if (l16 == 0) {
#pragma unroll
    for (int mi = 0; mi < 4; mi++)
#pragma unroll
      for (int r = 0; r < 4; r++) {
        int gm = m0 + wr * 64 + mi * 16 + quad * 4 + r;
        if (gm < M) {
          size_t o = ((size_t)rel * N_NODES + gm) * 4 + hh;  // [rel][n][4]
          el[o] = pel[mi][r];
          er[o] = per_[mi][r];
        }
      }
  }

  // ---- feat -> bf16 via LDS transpose, coalesced store (row stride 768) ----
#pragma unroll
  for (int mi = 0; mi < 4; mi++) {
    int row = wr * 64 + mi * 16 + quad * 4;
#pragma unroll
    for (int ni = 0; ni < 4; ni++) {
      int c = wc * 64 + ni * 16 + l16;
#pragma unroll
      for (int r = 0; r < 4; r++)
        lds[(row + r) * LDT + c] = f2bf(acc[mi][ni][r]);
    }
  }
  __syncthreads();
#pragma unroll
  for (int it = 0; it < 8; it++) {
    int chunk = tid + 256 * it;           // 0..2047
    int row = chunk >> 4, c8 = (chunk & 15) * 8;
    int gm = m0 + row;
    if (gm < M)
      *(uint4*)&Cb[(size_t)gm * 768 + n0 + c8] = *(const uint4*)&lds[row * LDT + c8];
  }
}

// ---------------- fused aggregation: small LDS alpha + R9-style gather ----------------
// Phase 1 (lanes=edges): unnormalized p -> LDS (9216 B, no occupancy hit),
// denominators wave-reduced. Phase 2: R9 inner loop (ushort4/lane, 2-edge
// unroll). Normalization after the sum (linear). deg>MAXDEG: recompute path.

__global__ void agg_kernel(const unsigned short* __restrict__ featb,
                           const float* __restrict__ el, const float* __restrict__ er,
                           const int* __restrict__ row_ptr, const int* __restrict__ col,
                           const float* __restrict__ bias,
                           unsigned short* __restrict__ hH, float* __restrict__ outF,
                           int final_layer) {
  __shared__ float salpha[4][N_REL][MAXDEG * 4];   // 9216 B
  int w = threadIdx.x >> 6;
  int n = blockIdx.x * 4 + w;
  int L = threadIdx.x & 63;
  if (n >= N_NODES) return;
  const int hsel = L >> 4;

  int s0r[N_REL], s1r[N_REL];
  float invsel[N_REL];
  float4 ernr[N_REL];
  // ---- phase 1 ----
#pragma unroll
  for (int r = 0; r < N_REL; r++) {
    int s0 = row_ptr[r * RP_STRIDE + n], s1 = row_ptr[r * RP_STRIDE + n + 1];
    s0r[r] = s0; s1r[r] = s1;
    int deg = s1 - s0;
    float4 ern = ((const float4*)er)[(size_t)r * N_NODES + n];
    ernr[r] = ern;
    const int* cp = col + (size_t)r * N_EDGES;
    bool fits = (deg <= MAXDEG);
    float d0 = 0.f, d1 = 0.f, d2 = 0.f, d3 = 0.f;
    for (int base = s0; base < s1; base += 64) {
      int i = base + L;
      if (i < s1) {
        int s = cp[i];
        float4 els = ((const float4*)el)[(size_t)r * N_NODES + s];
        float e0 = els.x + ern.x; e0 = e0 > 0.f ? e0 : NEG_SLOPE * e0;
        float e1 = els.y + ern.y; e1 = e1 > 0.f ? e1 : NEG_SLOPE * e1;
        float e2 = els.z + ern.z; e2 = e2 > 0.f ? e2 : NEG_SLOPE * e2;
        float e3 = els.w + ern.w; e3 = e3 > 0.f ? e3 : NEG_SLOPE * e3;
        float p0 = __expf(e0), p1 = __expf(e1), p2 = __expf(e2), p3 = __expf(e3);
        if (fits) *(float4*)&salpha[w][r][(i - s0) * 4] = make_float4(p0, p1, p2, p3);
        d0 += p0; d1 += p1; d2 += p2; d3 += p3;
      }
    }
#pragma unroll
    for (int o = 1; o < 64; o <<= 1) {
      d0 += __shfl_xor(d0, o); d1 += __shfl_xor(d1, o);
      d2 += __shfl_xor(d2, o); d3 += __shfl_xor(d3, o);
    }
    float dsel = (hsel == 0) ? d0 : (hsel == 1) ? d1 : (hsel == 2) ? d2 : d3;
    invsel[r] = 1.0f / fmaxf(dsel, 1e-30f);
  }

  // ---- phase 2 ----
  const float third = 1.0f / 3.0f;
  float os0 = 0.f, os1 = 0.f, os2 = 0.f, os3 = 0.f;
#pragma unroll
  for (int r = 0; r < N_REL; r++) {
    int s0 = s0r[r], s1 = s1r[r], deg = s1 - s0;
    const int* cp = col + (size_t)r * N_EDGES;
    const unsigned short* fbase = featb + r * 256 + 4 * L;
    float a0 = 0.f, a1 = 0.f, a2 = 0.f, a3 = 0.f;
    if (deg <= MAXDEG) {
      const float* ap = &salpha[w][r][0];
      int i = 0;
      for (; i + 1 < deg; i += 2) {
        int sA = cp[s0 + i], sB = cp[s0 + i + 1];
        float wA = ap[i * 4 + hsel];
        float wB = ap[(i + 1) * 4 + hsel];
        ushort4 fA = *(const ushort4*)&fbase[(size_t)sA * 768];
        ushort4 fB = *(const ushort4*)&fbase[(size_t)sB * 768];
        a0 += wA * bf2f(fA.x) + wB * bf2f(fB.x);
        a1 += wA * bf2f(fA.y) + wB * bf2f(fB.y);
        a2 += wA * bf2f(fA.z) + wB * bf2f(fB.z);
        a3 += wA * bf2f(fA.w) + wB * bf2f(fB.w);
      }
      if (i < deg) {
        int sA = cp[s0 + i];
        float wA = ap[i * 4 + hsel];
        ushort4 fA = *(const ushort4*)&fbase[(size_t)sA * 768];
        a0 += wA * bf2f(fA.x); a1 += wA * bf2f(fA.y);
        a2 += wA * bf2f(fA.z); a3 += wA * bf2f(fA.w);
      }
    } else {
      float4 ern = ernr[r];
      float ernh = (hsel == 0) ? ern.x : (hsel == 1) ? ern.y : (hsel == 2) ? ern.z : ern.w;
      for (int i = s0; i < s1; i++) {
        int s = cp[i];
        float4 els = ((const float4*)el)[(size_t)r * N_NODES + s];
        float elh = (hsel == 0) ? els.x : (hsel == 1) ? els.y : (hsel == 2) ? els.z : els.w;
        float e = elh + ernh; e = e > 0.f ? e : NEG_SLOPE * e;
        float pw = __expf(e);
        ushort4 fA = *(const ushort4*)&fbase[(size_t)s * 768];
        a0 += pw * bf2f(fA.x); a1 += pw * bf2f(fA.y);
        a2 += pw * bf2f(fA.z); a3 += pw * bf2f(fA.w);
      }
    }
    float inv = invsel[r];
    float4 bv = *(const float4*)&bias[r * 256 + 4 * L];
    float o0 = a0 * inv + bv.x, o1 = a1 * inv + bv.y;
    float o2 = a2 * inv + bv.z, o3 = a3 * inv + bv.w;
    o0 = o0 > 0.f ? o0 : __expf(o0) - 1.0f;  // elu
    o1 = o1 > 0.f ? o1 : __expf(o1) - 1.0f;
    o2 = o2 > 0.f ? o2 : __expf(o2) - 1.0f;
    o3 = o3 > 0.f ? o3 : __expf(o3) - 1.0f;
    os0 += o0 * third; os1 += o1 * third; os2 += o2 * third; os3 += o3 * third;
  }
  if (final_layer) {
#pragma unroll
    for (int o = 16; o <= 32; o <<= 1) {
      os0 += __shfl_xor(os0, o); os1 += __shfl_xor(os1, o);
      os2 += __shfl_xor(os2, o); os3 += __shfl_xor(os3, o);
    }
    if (L < 16)
      *(float4*)&outF[(size_t)n * 64 + L * 4] =
          make_float4(0.25f * os0, 0.25f * os1, 0.25f * os2, 0.25f * os3);
  } else {
    ushort4 h;
    h.x = f2bf(os0); h.y = f2bf(os1); h.z = f2bf(os2); h.w = f2bf(os3);
    *(ushort4*)&hH[(size_t)n * 256 + 4 * L] = h;
  }
}

// ---------------- launch ----------------

extern "C" void kernel_launch(void* const* d_in, const int* in_sizes, int n_in,
                              void* d_out, int out_size, void* d_ws, size_t ws_size,
                              hipStream_t stream) {
  (void)in_sizes; (void)n_in; (void)out_size; (void)ws_size;
  const float* x = (const float*)d_in[0];
  const int* src = (const int*)d_in[1];
  const int* dst = (const int*)d_in[2];
  const float* Wl[3]  = {(const float*)d_in[3], (const float*)d_in[7], (const float*)d_in[11]};
  const float* alL[3] = {(const float*)d_in[4], (const float*)d_in[8], (const float*)d_in[12]};
  const float* arL[3] = {(const float*)d_in[5], (const float*)d_in[9], (const float*)d_in[13]};
  const float* bL[3]  = {(const float*)d_in[6], (const float*)d_in[10], (const float*)d_in[14]};

  char* p = (char*)d_ws;
  auto alloc = [&](size_t bytes) {
    char* q = p;
    p += (bytes + 255) & ~size_t(255);
    return q;
  };
  unsigned short* xh = (unsigned short*)alloc((size_t)M_PAD * 256 * 2);
  unsigned short* hH = (unsigned short*)alloc((size_t)M_PAD * 256 * 2);
  unsigned short* featb = (unsigned short*)alloc((size_t)N_NODES * 768 * 2);
  float* el      = (float*)alloc((size_t)N_REL * N_NODES * 4 * 4);
  float* er      = (float*)alloc((size_t)N_REL * N_NODES * 4 * 4);
  int*   cnt     = (int*)alloc((size_t)N_REL * N_NODES * 4);
  int*   cursor  = (int*)alloc((size_t)N_REL * N_NODES * 4);
  int*   row_ptr = (int*)alloc((size_t)N_REL * RP_STRIDE * 4 + 64);
  int*   col     = (int*)alloc((size_t)N_REL * N_EDGES * 4);
  int*   psum    = (int*)alloc((size_t)N_REL * SCAN_BLOCKS * 4);
  unsigned short* Whi = (unsigned short*)alloc((size_t)9 * 65536 * 2);
  unsigned short* Wlo = (unsigned short*)alloc((size_t)9 * 65536 * 2);

  hipMemsetAsync(cnt, 0, (size_t)N_REL * N_NODES * 4, stream);
  const int totalE = N_REL * N_EDGES;
  count_kernel<<<(totalE + 255) / 256, 256, 0, stream>>>(dst, cnt, totalE);
  block_reduce_kernel<<<N_REL * SCAN_BLOCKS, 256, 0, stream>>>(cnt, psum);
  psum_scan_kernel<<<N_REL, 64, 0, stream>>>(psum, row_ptr);
  scan_write_kernel<<<N_REL * SCAN_BLOCKS, 256, 0, stream>>>(cnt, psum, row_ptr, cursor);
  scatter_kernel<<<(totalE + 255) / 256, 256, 0, stream>>>(src, dst, cursor, col, totalE);
  wsplit_kernel<<<9 * 64, 256, 0, stream>>>(Wl[0], Wl[1], Wl[2], Whi, Wlo);
  xsplit_kernel<<<M_PAD * 64 / 256, 256, 0, stream>>>(x, xh);

  const int nodeBlocks = (N_NODES + 3) / 4;
  const int gemmBlocks = MG_PER_XCD * 6 * 8;   // 2352
  for (int l = 0; l < 3; l++) {
    const unsigned short* Ahp = (l == 0) ? xh : hH;
    gemm_mfma_kernel<<<gemmBlocks, 256, 0, stream>>>(
        Ahp, Whi + (size_t)l * 3 * 65536, Wlo + (size_t)l * 3 * 65536,
        alL[l], arL[l], featb, el, er, N_NODES);
    agg_kernel<<<nodeBlocks, 256, 0, stream>>>(
        featb, el, er, row_ptr, col, bL[l], hH, (float*)d_out, l == 2);
  }
}